// Round 11
// baseline (431.073 us; speedup 1.0000x reference)
//
#include <hip/hip_runtime.h>
#include <hip/hip_bf16.h>
#include <math.h>

#define BGRAPH 128
#define NPER0 1024
#define DDIM 64
#define NTOT (BGRAPH*NPER0)      // 131072
#define ETOT (NTOT*16)           // 2097152
#define EPG  (ETOT/BGRAPH)       // 16384
#define KK1 820
#define KK2 656
#define KK3 525

__device__ __forceinline__ bool cmp_before(float va, int ia, float vb, int ib) {
    return (va > vb) || (va == vb && ia < ib);
}

// ---------- layer-1 tables ----------
__global__ void k_msg1_table(const float* __restrict__ emb, const float* __restrict__ W,
                             const float* __restrict__ b, float* __restrict__ msgT) {
    int id = blockIdx.x, d = threadIdx.x;
    float a = b[d];
    for (int k = 0; k < 64; k++) a = fmaf(emb[id * 64 + k], W[d * 64 + k], a);
    msgT[id * 64 + d] = fmaxf(a, 0.f);
}

__global__ void k_combo1_table(const float* __restrict__ msgT, const float* __restrict__ emb,
                               const float* __restrict__ U, const float* __restrict__ p,
                               float* __restrict__ s1T, float* __restrict__ x2T) {
    __shared__ float cat[128];
    int c = blockIdx.x, d = threadIdx.x;
    int mask = c >> 2, id = c & 3;
    float ag = -INFINITY;
    for (int i = 0; i < 4; i++) if (mask & (1 << i)) ag = fmaxf(ag, msgT[i * 64 + d]);
    if (mask == 0) ag = 0.f;
    cat[d] = ag; cat[64 + d] = emb[id * 64 + d];
    __syncthreads();
    float a = 0.f;
    for (int k = 0; k < 128; k++) a = fmaf(U[d * 128 + k], cat[k], a);
    a = fmaxf(a, 0.f);
    float pv = p[d];
    float nrm = pv * pv, sv = a * pv;
    #pragma unroll
    for (int o = 32; o > 0; o >>= 1) { nrm += __shfl_xor(nrm, o); sv += __shfl_xor(sv, o); }
    float sc = sv / sqrtf(nrm);
    if (d == 0) s1T[c] = sc;
    x2T[c * 64 + d] = a * tanhf(sc);
}

__global__ void k_msg2_table(const float* __restrict__ x2T, const float* __restrict__ W,
                             const float* __restrict__ b, float* __restrict__ msg2T) {
    int c = blockIdx.x, d = threadIdx.x;
    float a = b[d];
    for (int k = 0; k < 64; k++) a = fmaf(x2T[c * 64 + k], W[d * 64 + k], a);
    msg2T[c * 64 + d] = fmaxf(a, 0.f);
}

// ---------- L1 fused: per-graph LDS mask -> combo + score ----------
__global__ __launch_bounds__(1024) void k_mask_combo1(const int* __restrict__ eidx,
                                                      const int* __restrict__ ids,
                                                      const float* __restrict__ s1T,
                                                      int* __restrict__ combo1,
                                                      float* __restrict__ score) {
    __shared__ unsigned lmask[1024];
    __shared__ int lids[1024];
    int g = blockIdx.x, t = threadIdx.x;
    int nb = g * NPER0;
    lids[t] = ids[nb + t];
    lmask[t] = 0u;
    __syncthreads();
    const int* es = eidx + (size_t)g * EPG;
    const int* ed = eidx + ETOT + (size_t)g * EPG;
    for (int e = t; e < EPG; e += 1024)
        atomicOr(&lmask[ed[e] - nb], 1u << lids[es[e] - nb]);
    __syncthreads();
    int id = lids[t];
    int cb = (int)(((lmask[t] | (1u << id)) << 2) | (unsigned)id);
    combo1[nb + t] = cb;
    score[nb + t] = s1T[cb];
}

// ---------- topk: hybrid shuffle/LDS bitonic + inverse perm + edge compaction ----------
__global__ __launch_bounds__(1024) void k_topk(const float* __restrict__ score,
                                               int nper, int k,
                                               float* __restrict__ topv,
                                               int* __restrict__ topi,
                                               const int* __restrict__ rawsrc,
                                               const int* __restrict__ rawdst,
                                               const ushort2* __restrict__ ein2,
                                               const int* __restrict__ ecnt_in,
                                               ushort2* __restrict__ eout,
                                               int* __restrict__ ecnt_out,
                                               int mode) {
    __shared__ float sv[1024];
    __shared__ int   si[1024];
    __shared__ int   invl[1024];
    __shared__ int   scnt;
    int g = blockIdx.x, i = threadIdx.x;
    if (i == 0) scnt = 0;
    sv[i] = (i < nper) ? score[g * nper + i] : -INFINITY;
    si[i] = i;
    __syncthreads();
    float v = sv[i]; int ix = si[i];
    #pragma unroll
    for (int ksz = 2; ksz <= 64; ksz <<= 1) {
        bool up = (i & ksz) == 0;
        for (int j = ksz >> 1; j > 0; j >>= 1) {
            float ov = __shfl_xor(v, j);
            int   oi = __shfl_xor(ix, j);
            bool take = cmp_before(v, ix, ov, oi) ^ ((i & j) != 0) ^ (!up);
            if (!take) { v = ov; ix = oi; }
        }
    }
    sv[i] = v; si[i] = ix;
    __syncthreads();
    for (int ksz = 128; ksz <= 1024; ksz <<= 1) {
        bool up = (i & ksz) == 0;
        for (int j = ksz >> 1; j >= 64; j >>= 1) {
            int ixj = i ^ j;
            if (ixj > i) {
                float va = sv[i], vb = sv[ixj];
                int ia = si[i], ib = si[ixj];
                if (up != cmp_before(va, ia, vb, ib)) {
                    sv[i] = vb; sv[ixj] = va; si[i] = ib; si[ixj] = ia;
                }
            }
            __syncthreads();
        }
        v = sv[i]; ix = si[i];
        for (int j = 32; j > 0; j >>= 1) {
            float ov = __shfl_xor(v, j);
            int   oi = __shfl_xor(ix, j);
            bool take = cmp_before(v, ix, ov, oi) ^ ((i & j) != 0) ^ (!up);
            if (!take) { v = ov; ix = oi; }
        }
        sv[i] = v; si[i] = ix;
        __syncthreads();
    }
    if (i < k) { topv[g * 1024 + i] = sv[i]; topi[g * 1024 + i] = si[i]; }
    int s = si[i];
    if (s < nper) invl[s] = (i < k) ? i : -1;   // LOCAL new index
    if (mode == 2) return;
    __syncthreads();
    int pcin = (mode == 0) ? EPG : ecnt_in[g];
    for (int e = i; e < pcin; e += 1024) {
        int ns, nd;
        if (mode == 0) {
            ns = invl[rawsrc[(size_t)g * EPG + e] - g * nper];
            nd = invl[rawdst[(size_t)g * EPG + e] - g * nper];
        } else {
            ushort2 sd = ein2[(size_t)g * EPG + e];
            if (sd.x == 0xFFFFu) continue;
            ns = invl[sd.x]; nd = invl[sd.y];
        }
        if (ns >= 0 && nd >= 0) {
            int pos = atomicAdd(&scnt, 1);
            eout[(size_t)g * EPG + pos] = make_ushort2((unsigned short)ns, (unsigned short)nd);
        }
    }
    __syncthreads();
    int cnt = scnt;
    int pc = (cnt + 1023) & ~1023;
    for (int e2 = cnt + i; e2 < pc; e2 += 1024)
        eout[(size_t)g * EPG + e2] = make_ushort2(0xFFFFu, 0);
    if (i == 0) ecnt_out[g] = pc;
}

// ---------- L2 fused: per-graph LDS 64-bit mask aggregation -> aggr ----------
__global__ __launch_bounds__(1024) void k_mask_aggr2(const ushort2* __restrict__ edges,
                                                     const int* __restrict__ ecnt,
                                                     const int* __restrict__ combo2,
                                                     const float4* __restrict__ msg2T4,
                                                     float4* __restrict__ aggr4) {
    __shared__ float4 tab[1024];          // 64 x 16 f4 = 16 KB
    __shared__ unsigned mlo[KK1], mhi[KK1];
    __shared__ int lcombo[KK1];
    int g = blockIdx.x, t = threadIdx.x;
    tab[t] = msg2T4[t];
    for (int i2 = t; i2 < KK1; i2 += 1024) {
        int c = combo2[g * KK1 + i2];
        lcombo[i2] = c;
        mlo[i2] = (c < 32) ? (1u << c) : 0u;
        mhi[i2] = (c < 32) ? 0u : (1u << (c - 32));
    }
    __syncthreads();
    const ushort2* eb = edges + (size_t)g * EPG;
    int pc = ecnt[g];
    for (int e = t; e < pc; e += 1024) {
        ushort2 sd = eb[e];
        if (sd.x != 0xFFFFu) {
            int c = lcombo[sd.x];
            if (c < 32) atomicOr(&mlo[sd.y], 1u << c);
            else        atomicOr(&mhi[sd.y], 1u << (c - 32));
        }
    }
    __syncthreads();
    for (int i2 = t; i2 < KK1 * 16; i2 += 1024) {
        int node = i2 >> 4, f = i2 & 15;
        unsigned lo = mlo[node], hi = mhi[node];
        float4 a = make_float4(-INFINITY, -INFINITY, -INFINITY, -INFINITY);
        while (lo) {
            int bb = __ffs(lo) - 1; lo &= lo - 1;
            float4 w = tab[bb * 16 + f];
            a.x = fmaxf(a.x, w.x); a.y = fmaxf(a.y, w.y);
            a.z = fmaxf(a.z, w.z); a.w = fmaxf(a.w, w.w);
        }
        while (hi) {
            int bb = __ffs(hi) - 1; hi &= hi - 1;
            float4 w = tab[(32 + bb) * 16 + f];
            a.x = fmaxf(a.x, w.x); a.y = fmaxf(a.y, w.y);
            a.z = fmaxf(a.z, w.z); a.w = fmaxf(a.w, w.w);
        }
        aggr4[((size_t)g * KK1 + node) * 16 + f] = a;
    }
}

// ---------- dense kernels: lane-pair k-split, weights in LDS ----------
// Each pair of threads handles one node; lane h covers k-half. 128 nodes/block.
__global__ __launch_bounds__(256) void k_dense64(const float* __restrict__ x,
                                                 const float* __restrict__ W,
                                                 const float* __restrict__ b,
                                                 float* __restrict__ out) {
    __shared__ float4 Wsh[64 * 16];   // 16 KB
    int t = threadIdx.x;
    const float4* W4 = (const float4*)W;
    #pragma unroll
    for (int i = 0; i < 4; i++) Wsh[t + i * 256] = W4[t + i * 256];
    int h = t & 1;
    int node = blockIdx.x * 128 + (t >> 1);
    float4 xr[8];
    const float4* xp = (const float4*)(x + (size_t)node * 64) + h * 8;
    #pragma unroll
    for (int i = 0; i < 8; i++) xr[i] = xp[i];
    __syncthreads();
    float4* op = (float4*)(out + (size_t)node * 64);
    int kb = h * 8;
    #pragma unroll 1
    for (int d4 = 0; d4 < 16; d4++) {
        int d = d4 * 4;
        float a0 = 0.f, a1 = 0.f, a2 = 0.f, a3 = 0.f;
        #pragma unroll
        for (int kk = 0; kk < 8; kk++) {
            float4 xv = xr[kk];
            float4 w0 = Wsh[(d+0)*16+kb+kk], w1 = Wsh[(d+1)*16+kb+kk];
            float4 w2 = Wsh[(d+2)*16+kb+kk], w3 = Wsh[(d+3)*16+kb+kk];
            a0 = fmaf(w0.w,xv.w,fmaf(w0.z,xv.z,fmaf(w0.y,xv.y,fmaf(w0.x,xv.x,a0))));
            a1 = fmaf(w1.w,xv.w,fmaf(w1.z,xv.z,fmaf(w1.y,xv.y,fmaf(w1.x,xv.x,a1))));
            a2 = fmaf(w2.w,xv.w,fmaf(w2.z,xv.z,fmaf(w2.y,xv.y,fmaf(w2.x,xv.x,a2))));
            a3 = fmaf(w3.w,xv.w,fmaf(w3.z,xv.z,fmaf(w3.y,xv.y,fmaf(w3.x,xv.x,a3))));
        }
        a0 += __shfl_xor(a0, 1); a1 += __shfl_xor(a1, 1);
        a2 += __shfl_xor(a2, 1); a3 += __shfl_xor(a3, 1);
        if ((d4 >> 3) == h) {
            op[d4] = make_float4(fmaxf(a0 + b[d], 0.f), fmaxf(a1 + b[d+1], 0.f),
                                 fmaxf(a2 + b[d+2], 0.f), fmaxf(a3 + b[d+3], 0.f));
        }
    }
}

// h = relu(cat(aggr,x) @ U.T); score = h·p/||p||. Lane h=0 loads aggr (k 0..63),
// h=1 loads x (k 64..127).
__global__ __launch_bounds__(256) void k_dense128cat(const float* __restrict__ aggr,
                                                     const float* __restrict__ x,
                                                     const float* __restrict__ U,
                                                     const float* __restrict__ p,
                                                     float* __restrict__ out,
                                                     float* __restrict__ score) {
    __shared__ float4 Ush[64 * 32];   // 32 KB
    int t = threadIdx.x;
    const float4* U4 = (const float4*)U;
    #pragma unroll
    for (int i = 0; i < 8; i++) Ush[t + i * 256] = U4[t + i * 256];
    int h = t & 1;
    int node = blockIdx.x * 128 + (t >> 1);
    float4 xr[16];
    const float4* src = h ? (const float4*)(x + (size_t)node * 64)
                          : (const float4*)(aggr + (size_t)node * 64);
    #pragma unroll
    for (int i = 0; i < 16; i++) xr[i] = src[i];
    float pv = p[t & 63];
    float nrm = pv * pv;
    #pragma unroll
    for (int o = 32; o > 0; o >>= 1) nrm += __shfl_xor(nrm, o);
    nrm = sqrtf(nrm);
    __syncthreads();
    float4* op = (float4*)(out + (size_t)node * 64);
    float sacc = 0.f;
    int kb = h * 16;
    #pragma unroll 1
    for (int d4 = 0; d4 < 16; d4++) {
        int d = d4 * 4;
        float a0 = 0.f, a1 = 0.f, a2 = 0.f, a3 = 0.f;
        #pragma unroll
        for (int kk = 0; kk < 16; kk++) {
            float4 xv = xr[kk];
            float4 w0 = Ush[(d+0)*32+kb+kk], w1 = Ush[(d+1)*32+kb+kk];
            float4 w2 = Ush[(d+2)*32+kb+kk], w3 = Ush[(d+3)*32+kb+kk];
            a0 = fmaf(w0.w,xv.w,fmaf(w0.z,xv.z,fmaf(w0.y,xv.y,fmaf(w0.x,xv.x,a0))));
            a1 = fmaf(w1.w,xv.w,fmaf(w1.z,xv.z,fmaf(w1.y,xv.y,fmaf(w1.x,xv.x,a1))));
            a2 = fmaf(w2.w,xv.w,fmaf(w2.z,xv.z,fmaf(w2.y,xv.y,fmaf(w2.x,xv.x,a2))));
            a3 = fmaf(w3.w,xv.w,fmaf(w3.z,xv.z,fmaf(w3.y,xv.y,fmaf(w3.x,xv.x,a3))));
        }
        a0 += __shfl_xor(a0, 1); a1 += __shfl_xor(a1, 1);
        a2 += __shfl_xor(a2, 1); a3 += __shfl_xor(a3, 1);
        if ((d4 >> 3) == h) {
            a0 = fmaxf(a0, 0.f); a1 = fmaxf(a1, 0.f);
            a2 = fmaxf(a2, 0.f); a3 = fmaxf(a3, 0.f);
            sacc = fmaf(a0, p[d], fmaf(a1, p[d+1], fmaf(a2, p[d+2], fmaf(a3, p[d+3], sacc))));
            op[d4] = make_float4(a0, a1, a2, a3);
        }
    }
    sacc += __shfl_xor(sacc, 1);
    if (h == 0) score[node] = sacc / nrm;
}

// ---------- L3 edge aggregation (compacted ushort2 edges, LDS atomics) ----------
__global__ __launch_bounds__(1024) void k_edge_max(const ushort2* __restrict__ edges,
                                                   const int* __restrict__ ecnt,
                                                   const float4* __restrict__ msg4,
                                                   float4* __restrict__ aggr4,
                                                   int nper) {
    extern __shared__ unsigned smax[];
    int g = blockIdx.x, q = blockIdx.y, t = threadIdx.x;
    int nodebase = g * nper;
    int q4 = q * 4;
    for (int i = t; i < nper * 4; i += 1024) {
        int node = i >> 2, dd = (i & 3) * 4;
        float4 vv = msg4[(size_t)(nodebase + node) * 16 + q4 + (i & 3)];
        int b0 = node << 4, sw = node & 15;
        smax[b0 | ((dd+0) ^ sw)] = __float_as_uint(vv.x);
        smax[b0 | ((dd+1) ^ sw)] = __float_as_uint(vv.y);
        smax[b0 | ((dd+2) ^ sw)] = __float_as_uint(vv.z);
        smax[b0 | ((dd+3) ^ sw)] = __float_as_uint(vv.w);
    }
    __syncthreads();
    const ushort2* eb = edges + (size_t)g * EPG;
    int pc = ecnt[g];
    int f4 = t & 3, d4 = f4 * 4, es = t >> 2;
    for (int base = 0; base < pc; base += 1024) {
        ushort2 sd[4];
        float4 vv[4];
        #pragma unroll
        for (int u = 0; u < 4; u++) sd[u] = eb[base + u * 256 + es];
        #pragma unroll
        for (int u = 0; u < 4; u++)
            vv[u] = (sd[u].x != 0xFFFFu)
                  ? msg4[(size_t)(nodebase + sd[u].x) * 16 + q4 + f4]
                  : make_float4(0.f, 0.f, 0.f, 0.f);
        #pragma unroll
        for (int u = 0; u < 4; u++) {
            if (sd[u].x != 0xFFFFu) {
                int ln = sd[u].y;
                int b0 = ln << 4, sw = ln & 15;
                atomicMax(&smax[b0 | ((d4+0) ^ sw)], __float_as_uint(vv[u].x));
                atomicMax(&smax[b0 | ((d4+1) ^ sw)], __float_as_uint(vv[u].y));
                atomicMax(&smax[b0 | ((d4+2) ^ sw)], __float_as_uint(vv[u].z));
                atomicMax(&smax[b0 | ((d4+3) ^ sw)], __float_as_uint(vv[u].w));
            }
        }
    }
    __syncthreads();
    for (int i = t; i < nper * 4; i += 1024) {
        int node = i >> 2, dd = (i & 3) * 4;
        int b0 = node << 4, sw = node & 15;
        float4 vv;
        vv.x = __uint_as_float(smax[b0 | ((dd+0) ^ sw)]);
        vv.y = __uint_as_float(smax[b0 | ((dd+1) ^ sw)]);
        vv.z = __uint_as_float(smax[b0 | ((dd+2) ^ sw)]);
        vv.w = __uint_as_float(smax[b0 | ((dd+3) ^ sw)]);
        aggr4[(size_t)(nodebase + node) * 16 + q4 + (i & 3)] = vv;
    }
}

// ---------- gathers (+ fused readout) ----------
__global__ __launch_bounds__(1024) void k_gather1(const int* __restrict__ combo1,
                                                  const float* __restrict__ x2T,
                                                  const int* __restrict__ topi,
                                                  float* __restrict__ xnew,
                                                  int* __restrict__ combo2,
                                                  float* __restrict__ r,
                                                  int nper, int k) {
    __shared__ float smx[16][64], ssm[16][64];
    int g = blockIdx.x, t = threadIdx.x;
    int d = t & 63, c16 = t >> 6;
    float m = -INFINITY, s = 0.f;
    for (int j = c16; j < k; j += 16) {
        int src = topi[g * 1024 + j];
        int cb = combo1[g * nper + src];
        float v = x2T[cb * 64 + d];
        xnew[((size_t)g * k + j) * 64 + d] = v;
        if (d == 0) combo2[g * k + j] = cb;
        m = fmaxf(m, v); s += v;
    }
    smx[c16][d] = m; ssm[c16][d] = s;
    __syncthreads();
    if (c16 == 0) {
        #pragma unroll
        for (int u = 1; u < 16; u++) { m = fmaxf(m, smx[u][d]); s += ssm[u][d]; }
        r[g * 128 + d] = m;
        r[g * 128 + 64 + d] = s / (float)k;
    }
}

__global__ __launch_bounds__(1024) void k_gather_readout(const float* __restrict__ x,
                                                         const float* __restrict__ topv,
                                                         const int* __restrict__ topi,
                                                         float* __restrict__ xnew,
                                                         float* __restrict__ r,
                                                         int nper, int k) {
    __shared__ float sscale[1024];
    __shared__ float smx[16][64], ssm[16][64];
    int g = blockIdx.x, t = threadIdx.x;
    if (t < k) sscale[t] = tanhf(topv[g * 1024 + t]);
    __syncthreads();
    int d = t & 63, c = t >> 6;
    float m = -INFINITY, s = 0.f;
    for (int j = c; j < k; j += 16) {
        int src = topi[g * 1024 + j];
        float v = x[((size_t)(g * nper) + src) * 64 + d] * sscale[j];
        xnew[((size_t)g * k + j) * 64 + d] = v;
        m = fmaxf(m, v); s += v;
    }
    smx[c][d] = m; ssm[c][d] = s;
    __syncthreads();
    if (c == 0) {
        #pragma unroll
        for (int u = 1; u < 16; u++) { m = fmaxf(m, smx[u][d]); s += ssm[u][d]; }
        r[g * 128 + d] = m;
        r[g * 128 + 64 + d] = s / (float)k;
    }
}

__global__ void k_mlp(const float* __restrict__ r1, const float* __restrict__ r2,
                      const float* __restrict__ r3,
                      const float* __restrict__ l1W, const float* __restrict__ l1b,
                      const float* __restrict__ l2W, const float* __restrict__ l2b,
                      const float* __restrict__ l3W, const float* __restrict__ l3b,
                      float* __restrict__ out) {
    __shared__ float h[128], h1[64], h2[64];
    int g = blockIdx.x, d = threadIdx.x;
    h[d]      = r1[g*128 + d]      + r2[g*128 + d]      + r3[g*128 + d];
    h[d + 64] = r1[g*128 + 64 + d] + r2[g*128 + 64 + d] + r3[g*128 + 64 + d];
    __syncthreads();
    float a = l1b[d];
    for (int k = 0; k < 128; k++) a = fmaf(l1W[d*128 + k], h[k], a);
    h1[d] = fmaxf(a, 0.f);
    __syncthreads();
    a = l2b[d];
    for (int k = 0; k < 64; k++) a = fmaf(l2W[d*64 + k], h1[k], a);
    h2[d] = fmaxf(a, 0.f);
    __syncthreads();
    a = l3b[d];
    for (int k = 0; k < 64; k++) a = fmaf(l3W[d*64 + k], h2[k], a);
    out[g*64 + d] = 1.f / (1.f + expf(-a));
}

__global__ void k_batch(float* __restrict__ out) {
    int i = blockIdx.x * blockDim.x + threadIdx.x;
    if (i < BGRAPH * KK3) out[i] = (float)(i / KK3);
}

// ---------- launch ----------
extern "C" void kernel_launch(void* const* d_in, const int* in_sizes, int n_in,
                              void* d_out, int out_size, void* d_ws, size_t ws_size,
                              hipStream_t stream) {
    const int*   x_ids = (const int*)  d_in[0];
    const int*   eidx  = (const int*)  d_in[1];
    const float* emb   = (const float*)d_in[2];
    const float* W1 = (const float*)d_in[3];  const float* b1 = (const float*)d_in[4];
    const float* U1 = (const float*)d_in[5];  const float* p1 = (const float*)d_in[6];
    const float* W2 = (const float*)d_in[7];  const float* b2 = (const float*)d_in[8];
    const float* U2 = (const float*)d_in[9];  const float* p2 = (const float*)d_in[10];
    const float* W3 = (const float*)d_in[11]; const float* b3 = (const float*)d_in[12];
    const float* U3 = (const float*)d_in[13]; const float* p3 = (const float*)d_in[14];
    const float* l1W = (const float*)d_in[15]; const float* l1b = (const float*)d_in[16];
    const float* l2W = (const float*)d_in[17]; const float* l2b = (const float*)d_in[18];
    const float* l3W = (const float*)d_in[19]; const float* l3b = (const float*)d_in[20];

    float* ws    = (float*)d_ws;
    float* xA    = ws;
    float* xB    = xA + (size_t)NTOT * 64;
    float* xC    = xB + (size_t)NTOT * 64;
    float* score = xC + (size_t)NTOT * 64;
    float* topv  = score + NTOT;
    float* r1    = topv + BGRAPH * 1024;
    float* r2    = r1 + BGRAPH * 128;
    float* r3    = r2 + BGRAPH * 128;
    float* msgT  = r3 + BGRAPH * 128;          // 256
    float* s1T   = msgT + 256;                 // 64
    float* x2T   = s1T + 64;                   // 4096
    float* msg2T = x2T + 4096;                 // 4096
    ushort2* edgesB = (ushort2*)(msg2T + 4096);   // ETOT
    ushort2* edgesA = edgesB + ETOT;              // ETOT
    int* topi   = (int*)(edgesA + ETOT);          // 128*1024
    int* combo1 = topi + BGRAPH * 1024;           // NTOT
    int* combo2 = combo1 + NTOT;                  // BGRAPH*KK1
    int* ecnt1  = combo2 + BGRAPH * KK1;          // 128
    int* ecnt2  = ecnt1 + BGRAPH;                 // 128

    const int n2 = BGRAPH * KK1;   // 104960
    const int n3 = BGRAPH * KK2;   // 83968

    // ---- layer 1 (combo space, all-LDS mask) ----
    k_msg1_table<<<4, 64, 0, stream>>>(emb, W1, b1, msgT);
    k_combo1_table<<<64, 64, 0, stream>>>(msgT, emb, U1, p1, s1T, x2T);
    k_msg2_table<<<64, 64, 0, stream>>>(x2T, W2, b2, msg2T);
    k_mask_combo1<<<BGRAPH, 1024, 0, stream>>>(eidx, x_ids, s1T, combo1, score);
    k_topk<<<BGRAPH, 1024, 0, stream>>>(score, NPER0, KK1, topv, topi,
                                        eidx, eidx + ETOT, nullptr, nullptr,
                                        edgesB, ecnt1, 0);
    k_gather1<<<BGRAPH, 1024, 0, stream>>>(combo1, x2T, topi, xA, combo2, r1, NPER0, KK1);

    // ---- layer 2 (LDS 64-bit mask aggregation + real dense) ----
    k_mask_aggr2<<<BGRAPH, 1024, 0, stream>>>(edgesB, ecnt1, combo2,
                                              (const float4*)msg2T, (float4*)xC);
    k_dense128cat<<<n2 / 128, 256, 0, stream>>>(xC, xA, U2, p2, xB, score);
    k_topk<<<BGRAPH, 1024, 0, stream>>>(score, KK1, KK2, topv, topi,
                                        nullptr, nullptr, edgesB, ecnt1,
                                        edgesA, ecnt2, 1);
    k_gather_readout<<<BGRAPH, 1024, 0, stream>>>(xB, topv, topi, xC, r2, KK1, KK2);

    // ---- layer 3 (real) ----
    k_dense64<<<n3 / 128, 256, 0, stream>>>(xC, W3, b3, xB);
    k_edge_max<<<dim3(BGRAPH, 4), 1024, KK2 * 16 * sizeof(float), stream>>>(
        edgesA, ecnt2, (const float4*)xB, (float4*)xA, KK2);
    k_dense128cat<<<n3 / 128, 256, 0, stream>>>(xA, xC, U3, p3, xB, score);
    k_topk<<<BGRAPH, 1024, 0, stream>>>(score, KK2, KK3, topv, topi,
                                        nullptr, nullptr, nullptr, nullptr,
                                        nullptr, nullptr, 2);
    k_gather_readout<<<BGRAPH, 1024, 0, stream>>>(xB, topv, topi, xA, r3, KK2, KK3);

    k_mlp<<<BGRAPH, 64, 0, stream>>>(r1, r2, r3, l1W, l1b, l2W, l2b, l3W, l3b, (float*)d_out);
    k_batch<<<(BGRAPH * KK3 + 255) / 256, 256, 0, stream>>>((float*)d_out + BGRAPH * DDIM);
}

// Round 13
// 391.461 us; speedup vs baseline: 1.1012x; 1.1012x over previous
//
#include <hip/hip_runtime.h>
#include <hip/hip_bf16.h>
#include <math.h>

#define BGRAPH 128
#define NPER0 1024
#define DDIM 64
#define NTOT (BGRAPH*NPER0)      // 131072
#define ETOT (NTOT*16)           // 2097152
#define EPG  (ETOT/BGRAPH)       // 16384
#define KK1 820
#define KK2 656
#define KK3 525

__device__ __forceinline__ bool cmp_before(float va, int ia, float vb, int ib) {
    return (va > vb) || (va == vb && ia < ib);
}

// ---------- layer-1 tables ----------
__global__ void k_msg1_table(const float* __restrict__ emb, const float* __restrict__ W,
                             const float* __restrict__ b, float* __restrict__ msgT) {
    int id = blockIdx.x, d = threadIdx.x;
    float a = b[d];
    for (int k = 0; k < 64; k++) a = fmaf(emb[id * 64 + k], W[d * 64 + k], a);
    msgT[id * 64 + d] = fmaxf(a, 0.f);
}

__global__ void k_combo1_table(const float* __restrict__ msgT, const float* __restrict__ emb,
                               const float* __restrict__ U, const float* __restrict__ p,
                               float* __restrict__ s1T, float* __restrict__ x2T) {
    __shared__ float cat[128];
    int c = blockIdx.x, d = threadIdx.x;
    int mask = c >> 2, id = c & 3;
    float ag = -INFINITY;
    for (int i = 0; i < 4; i++) if (mask & (1 << i)) ag = fmaxf(ag, msgT[i * 64 + d]);
    if (mask == 0) ag = 0.f;
    cat[d] = ag; cat[64 + d] = emb[id * 64 + d];
    __syncthreads();
    float a = 0.f;
    for (int k = 0; k < 128; k++) a = fmaf(U[d * 128 + k], cat[k], a);
    a = fmaxf(a, 0.f);
    float pv = p[d];
    float nrm = pv * pv, sv = a * pv;
    #pragma unroll
    for (int o = 32; o > 0; o >>= 1) { nrm += __shfl_xor(nrm, o); sv += __shfl_xor(sv, o); }
    float sc = sv / sqrtf(nrm);
    if (d == 0) s1T[c] = sc;
    x2T[c * 64 + d] = a * tanhf(sc);
}

__global__ void k_msg2_table(const float* __restrict__ x2T, const float* __restrict__ W,
                             const float* __restrict__ b, float* __restrict__ msg2T) {
    int c = blockIdx.x, d = threadIdx.x;
    float a = b[d];
    for (int k = 0; k < 64; k++) a = fmaf(x2T[c * 64 + k], W[d * 64 + k], a);
    msg2T[c * 64 + d] = fmaxf(a, 0.f);
}

// ---------- L1 fused: per-graph LDS mask -> combo + score ----------
__global__ __launch_bounds__(1024) void k_mask_combo1(const int* __restrict__ eidx,
                                                      const int* __restrict__ ids,
                                                      const float* __restrict__ s1T,
                                                      int* __restrict__ combo1,
                                                      float* __restrict__ score) {
    __shared__ unsigned lmask[1024];
    __shared__ int lids[1024];
    int g = blockIdx.x, t = threadIdx.x;
    int nb = g * NPER0;
    lids[t] = ids[nb + t];
    lmask[t] = 0u;
    __syncthreads();
    const int* es = eidx + (size_t)g * EPG;
    const int* ed = eidx + ETOT + (size_t)g * EPG;
    for (int e = t; e < EPG; e += 1024)
        atomicOr(&lmask[ed[e] - nb], 1u << lids[es[e] - nb]);
    __syncthreads();
    int id = lids[t];
    int cb = (int)(((lmask[t] | (1u << id)) << 2) | (unsigned)id);
    combo1[nb + t] = cb;
    score[nb + t] = s1T[cb];
}

// ---------- topk: hybrid shuffle/LDS bitonic + inverse perm + edge compaction ----------
__global__ __launch_bounds__(1024) void k_topk(const float* __restrict__ score,
                                               int nper, int k,
                                               float* __restrict__ topv,
                                               int* __restrict__ topi,
                                               const int* __restrict__ rawsrc,
                                               const int* __restrict__ rawdst,
                                               const ushort2* __restrict__ ein2,
                                               const int* __restrict__ ecnt_in,
                                               ushort2* __restrict__ eout,
                                               int* __restrict__ ecnt_out,
                                               int mode) {
    __shared__ float sv[1024];
    __shared__ int   si[1024];
    __shared__ int   invl[1024];
    __shared__ int   scnt;
    int g = blockIdx.x, i = threadIdx.x;
    if (i == 0) scnt = 0;
    sv[i] = (i < nper) ? score[g * nper + i] : -INFINITY;
    si[i] = i;
    __syncthreads();
    float v = sv[i]; int ix = si[i];
    #pragma unroll
    for (int ksz = 2; ksz <= 64; ksz <<= 1) {
        bool up = (i & ksz) == 0;
        for (int j = ksz >> 1; j > 0; j >>= 1) {
            float ov = __shfl_xor(v, j);
            int   oi = __shfl_xor(ix, j);
            bool take = cmp_before(v, ix, ov, oi) ^ ((i & j) != 0) ^ (!up);
            if (!take) { v = ov; ix = oi; }
        }
    }
    sv[i] = v; si[i] = ix;
    __syncthreads();
    for (int ksz = 128; ksz <= 1024; ksz <<= 1) {
        bool up = (i & ksz) == 0;
        for (int j = ksz >> 1; j >= 64; j >>= 1) {
            int ixj = i ^ j;
            if (ixj > i) {
                float va = sv[i], vb = sv[ixj];
                int ia = si[i], ib = si[ixj];
                if (up != cmp_before(va, ia, vb, ib)) {
                    sv[i] = vb; sv[ixj] = va; si[i] = ib; si[ixj] = ia;
                }
            }
            __syncthreads();
        }
        v = sv[i]; ix = si[i];
        for (int j = 32; j > 0; j >>= 1) {
            float ov = __shfl_xor(v, j);
            int   oi = __shfl_xor(ix, j);
            bool take = cmp_before(v, ix, ov, oi) ^ ((i & j) != 0) ^ (!up);
            if (!take) { v = ov; ix = oi; }
        }
        sv[i] = v; si[i] = ix;
        __syncthreads();
    }
    if (i < k) { topv[g * 1024 + i] = sv[i]; topi[g * 1024 + i] = si[i]; }
    int s = si[i];
    if (s < nper) invl[s] = (i < k) ? i : -1;   // LOCAL new index
    if (mode == 2) return;
    __syncthreads();
    int pcin = (mode == 0) ? EPG : ecnt_in[g];
    for (int e = i; e < pcin; e += 1024) {
        int ns, nd;
        if (mode == 0) {
            ns = invl[rawsrc[(size_t)g * EPG + e] - g * nper];
            nd = invl[rawdst[(size_t)g * EPG + e] - g * nper];
        } else {
            ushort2 sd = ein2[(size_t)g * EPG + e];
            if (sd.x == 0xFFFFu) continue;
            ns = invl[sd.x]; nd = invl[sd.y];
        }
        if (ns >= 0 && nd >= 0) {
            int pos = atomicAdd(&scnt, 1);
            eout[(size_t)g * EPG + pos] = make_ushort2((unsigned short)ns, (unsigned short)nd);
        }
    }
    __syncthreads();
    int cnt = scnt;
    int pc = (cnt + 1023) & ~1023;
    for (int e2 = cnt + i; e2 < pc; e2 += 1024)
        eout[(size_t)g * EPG + e2] = make_ushort2(0xFFFFu, 0);
    if (i == 0) ecnt_out[g] = pc;
}

// ---------- L2 fused: per-graph LDS 64-bit mask aggregation -> aggr ----------
__global__ __launch_bounds__(1024) void k_mask_aggr2(const ushort2* __restrict__ edges,
                                                     const int* __restrict__ ecnt,
                                                     const int* __restrict__ combo2,
                                                     const float4* __restrict__ msg2T4,
                                                     float4* __restrict__ aggr4) {
    __shared__ float4 tab[1024];          // 64 x 16 f4 = 16 KB
    __shared__ unsigned mlo[KK1], mhi[KK1];
    __shared__ int lcombo[KK1];
    int g = blockIdx.x, t = threadIdx.x;
    tab[t] = msg2T4[t];
    for (int i2 = t; i2 < KK1; i2 += 1024) {
        int c = combo2[g * KK1 + i2];
        lcombo[i2] = c;
        mlo[i2] = (c < 32) ? (1u << c) : 0u;
        mhi[i2] = (c < 32) ? 0u : (1u << (c - 32));
    }
    __syncthreads();
    const ushort2* eb = edges + (size_t)g * EPG;
    int pc = ecnt[g];
    for (int e = t; e < pc; e += 1024) {
        ushort2 sd = eb[e];
        if (sd.x != 0xFFFFu) {
            int c = lcombo[sd.x];
            if (c < 32) atomicOr(&mlo[sd.y], 1u << c);
            else        atomicOr(&mhi[sd.y], 1u << (c - 32));
        }
    }
    __syncthreads();
    for (int i2 = t; i2 < KK1 * 16; i2 += 1024) {
        int node = i2 >> 4, f = i2 & 15;
        unsigned lo = mlo[node], hi = mhi[node];
        float4 a = make_float4(-INFINITY, -INFINITY, -INFINITY, -INFINITY);
        while (lo) {
            int bb = __ffs(lo) - 1; lo &= lo - 1;
            float4 w = tab[bb * 16 + f];
            a.x = fmaxf(a.x, w.x); a.y = fmaxf(a.y, w.y);
            a.z = fmaxf(a.z, w.z); a.w = fmaxf(a.w, w.w);
        }
        while (hi) {
            int bb = __ffs(hi) - 1; hi &= hi - 1;
            float4 w = tab[(32 + bb) * 16 + f];
            a.x = fmaxf(a.x, w.x); a.y = fmaxf(a.y, w.y);
            a.z = fmaxf(a.z, w.z); a.w = fmaxf(a.w, w.w);
        }
        aggr4[((size_t)g * KK1 + node) * 16 + f] = a;
    }
}

// ---------- dense kernels: lane-pair k-split, bank-padded LDS weights ----------
// Pair of lanes per node; lane h covers k-half h. Weight LDS layout
// [row][half][kk] with half-stride padded so the two lanes' addresses land in
// different banks (stride 9 f4 = 36 dwords, 36%32=4). Both lanes hold the full
// sum after shfl-combine; lane h stores outputs with d4&1==h (32B/pair).
__global__ __launch_bounds__(256) void k_dense64(const float* __restrict__ x,
                                                 const float* __restrict__ W,
                                                 const float* __restrict__ b,
                                                 float* __restrict__ out) {
    __shared__ float4 Wsh[64 * 18];   // 18.4 KB
    int t = threadIdx.x;
    const float4* W4 = (const float4*)W;
    #pragma unroll
    for (int i = 0; i < 4; i++) {
        int idx = t + i * 256;                      // 1024 f4 total
        int row = idx >> 4, half = (idx >> 3) & 1, kk = idx & 7;
        Wsh[row * 18 + half * 9 + kk] = W4[idx];
    }
    int h = t & 1;
    int node = blockIdx.x * 128 + (t >> 1);
    float4 xr[8];
    const float4* xp = (const float4*)(x + (size_t)node * 64) + h * 8;
    #pragma unroll
    for (int i = 0; i < 8; i++) xr[i] = xp[i];
    __syncthreads();
    float4* op = (float4*)(out + (size_t)node * 64);
    const float4* wb = Wsh + h * 9;
    #pragma unroll 1
    for (int d4 = 0; d4 < 16; d4++) {
        int d = d4 * 4;
        float a0 = 0.f, a1 = 0.f, a2 = 0.f, a3 = 0.f;
        #pragma unroll
        for (int kk = 0; kk < 8; kk++) {
            float4 xv = xr[kk];
            float4 w0 = wb[(d+0)*18+kk], w1 = wb[(d+1)*18+kk];
            float4 w2 = wb[(d+2)*18+kk], w3 = wb[(d+3)*18+kk];
            a0 = fmaf(w0.w,xv.w,fmaf(w0.z,xv.z,fmaf(w0.y,xv.y,fmaf(w0.x,xv.x,a0))));
            a1 = fmaf(w1.w,xv.w,fmaf(w1.z,xv.z,fmaf(w1.y,xv.y,fmaf(w1.x,xv.x,a1))));
            a2 = fmaf(w2.w,xv.w,fmaf(w2.z,xv.z,fmaf(w2.y,xv.y,fmaf(w2.x,xv.x,a2))));
            a3 = fmaf(w3.w,xv.w,fmaf(w3.z,xv.z,fmaf(w3.y,xv.y,fmaf(w3.x,xv.x,a3))));
        }
        a0 += __shfl_xor(a0, 1); a1 += __shfl_xor(a1, 1);
        a2 += __shfl_xor(a2, 1); a3 += __shfl_xor(a3, 1);
        if ((d4 & 1) == h) {
            op[d4] = make_float4(fmaxf(a0 + b[d], 0.f), fmaxf(a1 + b[d+1], 0.f),
                                 fmaxf(a2 + b[d+2], 0.f), fmaxf(a3 + b[d+3], 0.f));
        }
    }
}

// h = relu(cat(aggr,x) @ U.T); score = h·p/||p||. Lane h=0: aggr half (k 0..63),
// h=1: x half (k 64..127). Half-stride 17 f4 = 68 dwords, 68%32=4 -> no conflict.
__global__ __launch_bounds__(256) void k_dense128cat(const float* __restrict__ aggr,
                                                     const float* __restrict__ x,
                                                     const float* __restrict__ U,
                                                     const float* __restrict__ p,
                                                     float* __restrict__ out,
                                                     float* __restrict__ score) {
    __shared__ float4 Ush[64 * 34];   // 34.8 KB
    int t = threadIdx.x;
    const float4* U4 = (const float4*)U;
    #pragma unroll
    for (int i = 0; i < 8; i++) {
        int idx = t + i * 256;                      // 2048 f4 total
        int row = idx >> 5, half = (idx >> 4) & 1, kk = idx & 15;
        Ush[row * 34 + half * 17 + kk] = U4[idx];
    }
    int h = t & 1;
    int node = blockIdx.x * 128 + (t >> 1);
    float4 xr[16];
    const float4* src = h ? (const float4*)(x + (size_t)node * 64)
                          : (const float4*)(aggr + (size_t)node * 64);
    #pragma unroll
    for (int i = 0; i < 16; i++) xr[i] = src[i];
    float pv = p[t & 63];
    float nrm = pv * pv;
    #pragma unroll
    for (int o = 32; o > 0; o >>= 1) nrm += __shfl_xor(nrm, o);
    nrm = sqrtf(nrm);
    __syncthreads();
    float4* op = (float4*)(out + (size_t)node * 64);
    const float4* wb = Ush + h * 17;
    float sacc = 0.f;
    #pragma unroll 1
    for (int d4 = 0; d4 < 16; d4++) {
        int d = d4 * 4;
        float a0 = 0.f, a1 = 0.f, a2 = 0.f, a3 = 0.f;
        #pragma unroll
        for (int kk = 0; kk < 16; kk++) {
            float4 xv = xr[kk];
            float4 w0 = wb[(d+0)*34+kk], w1 = wb[(d+1)*34+kk];
            float4 w2 = wb[(d+2)*34+kk], w3 = wb[(d+3)*34+kk];
            a0 = fmaf(w0.w,xv.w,fmaf(w0.z,xv.z,fmaf(w0.y,xv.y,fmaf(w0.x,xv.x,a0))));
            a1 = fmaf(w1.w,xv.w,fmaf(w1.z,xv.z,fmaf(w1.y,xv.y,fmaf(w1.x,xv.x,a1))));
            a2 = fmaf(w2.w,xv.w,fmaf(w2.z,xv.z,fmaf(w2.y,xv.y,fmaf(w2.x,xv.x,a2))));
            a3 = fmaf(w3.w,xv.w,fmaf(w3.z,xv.z,fmaf(w3.y,xv.y,fmaf(w3.x,xv.x,a3))));
        }
        a0 += __shfl_xor(a0, 1); a1 += __shfl_xor(a1, 1);
        a2 += __shfl_xor(a2, 1); a3 += __shfl_xor(a3, 1);
        if ((d4 & 1) == h) {
            a0 = fmaxf(a0, 0.f); a1 = fmaxf(a1, 0.f);
            a2 = fmaxf(a2, 0.f); a3 = fmaxf(a3, 0.f);
            sacc = fmaf(a0, p[d], fmaf(a1, p[d+1], fmaf(a2, p[d+2], fmaf(a3, p[d+3], sacc))));
            op[d4] = make_float4(a0, a1, a2, a3);
        }
    }
    sacc += __shfl_xor(sacc, 1);
    if (h == 0) score[node] = sacc / nrm;
}

// ---------- L3 edge aggregation (compacted ushort2 edges, LDS atomics) ----------
__global__ __launch_bounds__(1024) void k_edge_max(const ushort2* __restrict__ edges,
                                                   const int* __restrict__ ecnt,
                                                   const float4* __restrict__ msg4,
                                                   float4* __restrict__ aggr4,
                                                   int nper) {
    extern __shared__ unsigned smax[];
    int g = blockIdx.x, q = blockIdx.y, t = threadIdx.x;
    int nodebase = g * nper;
    int q4 = q * 4;
    for (int i = t; i < nper * 4; i += 1024) {
        int node = i >> 2, dd = (i & 3) * 4;
        float4 vv = msg4[(size_t)(nodebase + node) * 16 + q4 + (i & 3)];
        int b0 = node << 4, sw = node & 15;
        smax[b0 | ((dd+0) ^ sw)] = __float_as_uint(vv.x);
        smax[b0 | ((dd+1) ^ sw)] = __float_as_uint(vv.y);
        smax[b0 | ((dd+2) ^ sw)] = __float_as_uint(vv.z);
        smax[b0 | ((dd+3) ^ sw)] = __float_as_uint(vv.w);
    }
    __syncthreads();
    const ushort2* eb = edges + (size_t)g * EPG;
    int pc = ecnt[g];
    int f4 = t & 3, d4 = f4 * 4, es = t >> 2;
    for (int base = 0; base < pc; base += 1024) {
        ushort2 sd[4];
        float4 vv[4];
        #pragma unroll
        for (int u = 0; u < 4; u++) sd[u] = eb[base + u * 256 + es];
        #pragma unroll
        for (int u = 0; u < 4; u++)
            vv[u] = (sd[u].x != 0xFFFFu)
                  ? msg4[(size_t)(nodebase + sd[u].x) * 16 + q4 + f4]
                  : make_float4(0.f, 0.f, 0.f, 0.f);
        #pragma unroll
        for (int u = 0; u < 4; u++) {
            if (sd[u].x != 0xFFFFu) {
                int ln = sd[u].y;
                int b0 = ln << 4, sw = ln & 15;
                atomicMax(&smax[b0 | ((d4+0) ^ sw)], __float_as_uint(vv[u].x));
                atomicMax(&smax[b0 | ((d4+1) ^ sw)], __float_as_uint(vv[u].y));
                atomicMax(&smax[b0 | ((d4+2) ^ sw)], __float_as_uint(vv[u].z));
                atomicMax(&smax[b0 | ((d4+3) ^ sw)], __float_as_uint(vv[u].w));
            }
        }
    }
    __syncthreads();
    for (int i = t; i < nper * 4; i += 1024) {
        int node = i >> 2, dd = (i & 3) * 4;
        int b0 = node << 4, sw = node & 15;
        float4 vv;
        vv.x = __uint_as_float(smax[b0 | ((dd+0) ^ sw)]);
        vv.y = __uint_as_float(smax[b0 | ((dd+1) ^ sw)]);
        vv.z = __uint_as_float(smax[b0 | ((dd+2) ^ sw)]);
        vv.w = __uint_as_float(smax[b0 | ((dd+3) ^ sw)]);
        aggr4[(size_t)(nodebase + node) * 16 + q4 + (i & 3)] = vv;
    }
}

// ---------- gathers (+ fused readout) ----------
__global__ __launch_bounds__(1024) void k_gather1(const int* __restrict__ combo1,
                                                  const float* __restrict__ x2T,
                                                  const int* __restrict__ topi,
                                                  float* __restrict__ xnew,
                                                  int* __restrict__ combo2,
                                                  float* __restrict__ r,
                                                  int nper, int k) {
    __shared__ float smx[16][64], ssm[16][64];
    int g = blockIdx.x, t = threadIdx.x;
    int d = t & 63, c16 = t >> 6;
    float m = -INFINITY, s = 0.f;
    for (int j = c16; j < k; j += 16) {
        int src = topi[g * 1024 + j];
        int cb = combo1[g * nper + src];
        float v = x2T[cb * 64 + d];
        xnew[((size_t)g * k + j) * 64 + d] = v;
        if (d == 0) combo2[g * k + j] = cb;
        m = fmaxf(m, v); s += v;
    }
    smx[c16][d] = m; ssm[c16][d] = s;
    __syncthreads();
    if (c16 == 0) {
        #pragma unroll
        for (int u = 1; u < 16; u++) { m = fmaxf(m, smx[u][d]); s += ssm[u][d]; }
        r[g * 128 + d] = m;
        r[g * 128 + 64 + d] = s / (float)k;
    }
}

__global__ __launch_bounds__(1024) void k_gather_readout(const float* __restrict__ x,
                                                         const float* __restrict__ topv,
                                                         const int* __restrict__ topi,
                                                         float* __restrict__ xnew,
                                                         float* __restrict__ r,
                                                         int nper, int k) {
    __shared__ float sscale[1024];
    __shared__ float smx[16][64], ssm[16][64];
    int g = blockIdx.x, t = threadIdx.x;
    if (t < k) sscale[t] = tanhf(topv[g * 1024 + t]);
    __syncthreads();
    int d = t & 63, c = t >> 6;
    float m = -INFINITY, s = 0.f;
    for (int j = c; j < k; j += 16) {
        int src = topi[g * 1024 + j];
        float v = x[((size_t)(g * nper) + src) * 64 + d] * sscale[j];
        xnew[((size_t)g * k + j) * 64 + d] = v;
        m = fmaxf(m, v); s += v;
    }
    smx[c][d] = m; ssm[c][d] = s;
    __syncthreads();
    if (c == 0) {
        #pragma unroll
        for (int u = 1; u < 16; u++) { m = fmaxf(m, smx[u][d]); s += ssm[u][d]; }
        r[g * 128 + d] = m;
        r[g * 128 + 64 + d] = s / (float)k;
    }
}

__global__ void k_mlp(const float* __restrict__ r1, const float* __restrict__ r2,
                      const float* __restrict__ r3,
                      const float* __restrict__ l1W, const float* __restrict__ l1b,
                      const float* __restrict__ l2W, const float* __restrict__ l2b,
                      const float* __restrict__ l3W, const float* __restrict__ l3b,
                      float* __restrict__ out) {
    __shared__ float h[128], h1[64], h2[64];
    int g = blockIdx.x, d = threadIdx.x;
    h[d]      = r1[g*128 + d]      + r2[g*128 + d]      + r3[g*128 + d];
    h[d + 64] = r1[g*128 + 64 + d] + r2[g*128 + 64 + d] + r3[g*128 + 64 + d];
    __syncthreads();
    float a = l1b[d];
    for (int k = 0; k < 128; k++) a = fmaf(l1W[d*128 + k], h[k], a);
    h1[d] = fmaxf(a, 0.f);
    __syncthreads();
    a = l2b[d];
    for (int k = 0; k < 64; k++) a = fmaf(l2W[d*64 + k], h1[k], a);
    h2[d] = fmaxf(a, 0.f);
    __syncthreads();
    a = l3b[d];
    for (int k = 0; k < 64; k++) a = fmaf(l3W[d*64 + k], h2[k], a);
    out[g*64 + d] = 1.f / (1.f + expf(-a));
}

__global__ void k_batch(float* __restrict__ out) {
    int i = blockIdx.x * blockDim.x + threadIdx.x;
    if (i < BGRAPH * KK3) out[i] = (float)(i / KK3);
}

// ---------- launch ----------
extern "C" void kernel_launch(void* const* d_in, const int* in_sizes, int n_in,
                              void* d_out, int out_size, void* d_ws, size_t ws_size,
                              hipStream_t stream) {
    const int*   x_ids = (const int*)  d_in[0];
    const int*   eidx  = (const int*)  d_in[1];
    const float* emb   = (const float*)d_in[2];
    const float* W1 = (const float*)d_in[3];  const float* b1 = (const float*)d_in[4];
    const float* U1 = (const float*)d_in[5];  const float* p1 = (const float*)d_in[6];
    const float* W2 = (const float*)d_in[7];  const float* b2 = (const float*)d_in[8];
    const float* U2 = (const float*)d_in[9];  const float* p2 = (const float*)d_in[10];
    const float* W3 = (const float*)d_in[11]; const float* b3 = (const float*)d_in[12];
    const float* U3 = (const float*)d_in[13]; const float* p3 = (const float*)d_in[14];
    const float* l1W = (const float*)d_in[15]; const float* l1b = (const float*)d_in[16];
    const float* l2W = (const float*)d_in[17]; const float* l2b = (const float*)d_in[18];
    const float* l3W = (const float*)d_in[19]; const float* l3b = (const float*)d_in[20];

    float* ws    = (float*)d_ws;
    float* xA    = ws;
    float* xB    = xA + (size_t)NTOT * 64;
    float* xC    = xB + (size_t)NTOT * 64;
    float* score = xC + (size_t)NTOT * 64;
    float* topv  = score + NTOT;
    float* r1    = topv + BGRAPH * 1024;
    float* r2    = r1 + BGRAPH * 128;
    float* r3    = r2 + BGRAPH * 128;
    float* msgT  = r3 + BGRAPH * 128;          // 256
    float* s1T   = msgT + 256;                 // 64
    float* x2T   = s1T + 64;                   // 4096
    float* msg2T = x2T + 4096;                 // 4096
    ushort2* edgesB = (ushort2*)(msg2T + 4096);   // ETOT
    ushort2* edgesA = edgesB + ETOT;              // ETOT
    int* topi   = (int*)(edgesA + ETOT);          // 128*1024
    int* combo1 = topi + BGRAPH * 1024;           // NTOT
    int* combo2 = combo1 + NTOT;                  // BGRAPH*KK1
    int* ecnt1  = combo2 + BGRAPH * KK1;          // 128
    int* ecnt2  = ecnt1 + BGRAPH;                 // 128

    const int n2 = BGRAPH * KK1;   // 104960
    const int n3 = BGRAPH * KK2;   // 83968

    // ---- layer 1 (combo space, all-LDS mask) ----
    k_msg1_table<<<4, 64, 0, stream>>>(emb, W1, b1, msgT);
    k_combo1_table<<<64, 64, 0, stream>>>(msgT, emb, U1, p1, s1T, x2T);
    k_msg2_table<<<64, 64, 0, stream>>>(x2T, W2, b2, msg2T);
    k_mask_combo1<<<BGRAPH, 1024, 0, stream>>>(eidx, x_ids, s1T, combo1, score);
    k_topk<<<BGRAPH, 1024, 0, stream>>>(score, NPER0, KK1, topv, topi,
                                        eidx, eidx + ETOT, nullptr, nullptr,
                                        edgesB, ecnt1, 0);
    k_gather1<<<BGRAPH, 1024, 0, stream>>>(combo1, x2T, topi, xA, combo2, r1, NPER0, KK1);

    // ---- layer 2 (LDS 64-bit mask aggregation + real dense) ----
    k_mask_aggr2<<<BGRAPH, 1024, 0, stream>>>(edgesB, ecnt1, combo2,
                                              (const float4*)msg2T, (float4*)xC);
    k_dense128cat<<<n2 / 128, 256, 0, stream>>>(xC, xA, U2, p2, xB, score);
    k_topk<<<BGRAPH, 1024, 0, stream>>>(score, KK1, KK2, topv, topi,
                                        nullptr, nullptr, edgesB, ecnt1,
                                        edgesA, ecnt2, 1);
    k_gather_readout<<<BGRAPH, 1024, 0, stream>>>(xB, topv, topi, xC, r2, KK1, KK2);

    // ---- layer 3 (real) ----
    k_dense64<<<n3 / 128, 256, 0, stream>>>(xC, W3, b3, xB);
    k_edge_max<<<dim3(BGRAPH, 4), 1024, KK2 * 16 * sizeof(float), stream>>>(
        edgesA, ecnt2, (const float4*)xB, (float4*)xA, KK2);
    k_dense128cat<<<n3 / 128, 256, 0, stream>>>(xA, xC, U3, p3, xB, score);
    k_topk<<<BGRAPH, 1024, 0, stream>>>(score, KK2, KK3, topv, topi,
                                        nullptr, nullptr, nullptr, nullptr,
                                        nullptr, nullptr, 2);
    k_gather_readout<<<BGRAPH, 1024, 0, stream>>>(xB, topv, topi, xA, r3, KK2, KK3);

    k_mlp<<<BGRAPH, 64, 0, stream>>>(r1, r2, r3, l1W, l1b, l2W, l2b, l3W, l3b, (float*)d_out);
    k_batch<<<(BGRAPH * KK3 + 255) / 256, 256, 0, stream>>>((float*)d_out + BGRAPH * DDIM);
}